// Round 1
// 705.846 us; speedup vs baseline: 2.2980x; 2.2980x over previous
//
#include <hip/hip_runtime.h>
#include <hip/hip_bf16.h>

// Problem constants: B=8, N=10000, E=160000, F=128, H=256
#define Bn 8
#define Nn 10000
#define En 160000
#define Fn 128
#define Hn 256
#define NROW (Bn * Nn)     // 80,000
#define NEDGE (Bn * En)    // 1,280,000
#define TM 32              // rows per block in k_fused

// Dtype model (verified PASS earlier): all float tensors f32, edges int32
// (inline int64 probe), output f32. AGG (f32 aggregate) strided inside
// d_out: AGG row r = first 128 floats of out row r (out + 256*r).
//
// R11 change: scatter-with-164M-f32-atomics (1040us, atomic-throughput
// bound: HBM 18%, VALU 10%) replaced by CSR build + gather. Workspace
// layout (ints):
//   [0,80000)            deg (f32) -> dinv after k_scan3
//   [80000,160001)       row_start (exclusive prefix of in-degree)
//   [160004,240004)      cursor (bin write positions; after k_bin = row end)
//   [240004,1520004)     elist (global src index per edge, CSR order)
//   [1520004,1520317)    bsum (313 block sums)
//   [1520320,1520832)    boff (512 block offsets)
#define OFF_RS  80000
#define OFF_CUR 160004
#define OFF_EL  240004
#define OFF_BS  1520004
#define OFF_BO  1520320
#define WS_INTS 1520832

__global__ void k_canary(float* out) {
    if (threadIdx.x == 0 && blockIdx.x == 0)
        out[4] = 1000.0f;   // erased by k_gather / k_agg_init
}

// ---------------------------------------------------------------------------
// Degree: 1 (self-loop) + #incoming edges.
// ---------------------------------------------------------------------------
__global__ void k_deg_init(float* __restrict__ deg) {
    int i = blockIdx.x * blockDim.x + threadIdx.x;
    if (i < NROW) deg[i] = 1.0f;
}

__device__ __forceinline__ bool edge_is_i64(const int* e) {
    return e[1] == 0 && e[3] == 0;
}
__device__ __forceinline__ int eidx(const int* e, long long i, bool i64) {
    return i64 ? e[2 * i] : e[i];
}

__global__ void k_deg_count(const int* __restrict__ e, float* __restrict__ deg) {
    bool i64 = edge_is_i64(e);
    int i = blockIdx.x * blockDim.x + threadIdx.x;
    if (i >= NEDGE) return;
    int b = i / En, k = i - b * En;
    int dst = eidx(e, (long long)(b * 2 + 1) * En + k, i64);
    if ((unsigned)dst < Nn) atomicAdd(&deg[b * Nn + dst], 1.0f);
}

__global__ void k_dinv(float* __restrict__ deg) {   // fallback path only
    int i = blockIdx.x * blockDim.x + threadIdx.x;
    if (i < NROW) deg[i] = rsqrtf(deg[i]);
}

// ---------------------------------------------------------------------------
// Exclusive scan of in-degree (deg[i]-1) over 80,000 rows, 3 kernels.
// ---------------------------------------------------------------------------
__global__ void k_scan1(const float* __restrict__ deg,
                        int* __restrict__ row_start, int* __restrict__ bsum) {
    __shared__ int s[256];
    int i = blockIdx.x * 256 + threadIdx.x;
    int v = (i < NROW) ? ((int)deg[i] - 1) : 0;
    s[threadIdx.x] = v;
    __syncthreads();
    for (int off = 1; off < 256; off <<= 1) {
        int t = (threadIdx.x >= off) ? s[threadIdx.x - off] : 0;
        __syncthreads();
        s[threadIdx.x] += t;
        __syncthreads();
    }
    if (i < NROW) row_start[i] = s[threadIdx.x] - v;   // exclusive within block
    if (threadIdx.x == 255) bsum[blockIdx.x] = s[255];
}

__global__ void k_scan2(const int* __restrict__ bsum, int* __restrict__ boff,
                        int* __restrict__ row_start) {
    __shared__ int s[512];
    int t = threadIdx.x;                               // 512 threads
    int v = (t < 313) ? bsum[t] : 0;
    s[t] = v;
    __syncthreads();
    for (int off = 1; off < 512; off <<= 1) {
        int u = (t >= off) ? s[t - off] : 0;
        __syncthreads();
        s[t] += u;
        __syncthreads();
    }
    boff[t] = s[t] - v;                                // exclusive block offset
    if (t == 511) row_start[NROW] = s[511];            // total valid edges
}

// Finalize row_start, init cursor, and compute dinv in one pass.
__global__ void k_scan3(float* __restrict__ deg, int* __restrict__ row_start,
                        const int* __restrict__ boff, int* __restrict__ cursor) {
    int i = blockIdx.x * blockDim.x + threadIdx.x;
    if (i >= NROW) return;
    int v = row_start[i] + boff[i >> 8];
    row_start[i] = v;
    cursor[i] = v;
    deg[i] = rsqrtf(deg[i]);
}

// ---------------------------------------------------------------------------
// Counting-sort edges by destination: elist[pos] = global src index.
// ---------------------------------------------------------------------------
__global__ void k_bin(const int* __restrict__ e, int* __restrict__ cursor,
                      int* __restrict__ elist) {
    bool i64 = edge_is_i64(e);
    int i = blockIdx.x * blockDim.x + threadIdx.x;
    if (i >= NEDGE) return;
    int b = i / En, k = i - b * En;
    int src = eidx(e, (long long)(b * 2) * En + k, i64);
    int dst = eidx(e, (long long)(b * 2 + 1) * En + k, i64);
    if ((unsigned)src >= Nn || (unsigned)dst >= Nn) return;   // safety clamp
    int pos = atomicAdd(&cursor[b * Nn + dst], 1);
    elist[pos] = b * Nn + src;
}

// ---------------------------------------------------------------------------
// Gather aggregation: one wave per destination row, 2 cols/lane.
//   AGG[r] = dinv[r] * ( sum_{src in row r} dinv[src]*x0[src] + dinv[r]*x0[r] )
// Writes every AGG slot (erases poison). Zero f32 atomics; x0 (41 MB) is
// L2/L3-resident so the random gathers stay on-chip.
// ---------------------------------------------------------------------------
__global__ __launch_bounds__(256) void k_gather(
        const float* __restrict__ x0, const float* __restrict__ dinv,
        const int* __restrict__ row_start, const int* __restrict__ row_end,
        const int* __restrict__ elist, float* __restrict__ out) {
    int wid = (blockIdx.x * 256 + threadIdx.x) >> 6;   // global wave id = row
    int lane = threadIdx.x & 63;
    if (wid >= NROW) return;
    int rs = row_start[wid], re = row_end[wid];        // re from cursor post-bin
    float ax = 0.f, ay = 0.f;
    int j = rs;
    for (; j + 4 <= re; j += 4) {                      // 4 independent chains
        int s0 = elist[j], s1 = elist[j + 1], s2 = elist[j + 2], s3 = elist[j + 3];
        float w0 = dinv[s0], w1 = dinv[s1], w2 = dinv[s2], w3 = dinv[s3];
        const float2 v0 = *(const float2*)(x0 + ((size_t)s0 << 7) + 2 * lane);
        const float2 v1 = *(const float2*)(x0 + ((size_t)s1 << 7) + 2 * lane);
        const float2 v2 = *(const float2*)(x0 + ((size_t)s2 << 7) + 2 * lane);
        const float2 v3 = *(const float2*)(x0 + ((size_t)s3 << 7) + 2 * lane);
        ax = fmaf(w0, v0.x, ax); ay = fmaf(w0, v0.y, ay);
        ax = fmaf(w1, v1.x, ax); ay = fmaf(w1, v1.y, ay);
        ax = fmaf(w2, v2.x, ax); ay = fmaf(w2, v2.y, ay);
        ax = fmaf(w3, v3.x, ax); ay = fmaf(w3, v3.y, ay);
    }
    for (; j < re; ++j) {
        int s = elist[j];
        float w = dinv[s];
        const float2 v = *(const float2*)(x0 + ((size_t)s << 7) + 2 * lane);
        ax = fmaf(w, v.x, ax); ay = fmaf(w, v.y, ay);
    }
    float wd = dinv[wid];
    const float2 xv = *(const float2*)(x0 + ((size_t)wid << 7) + 2 * lane);
    float2 r;
    r.x = wd * fmaf(wd, xv.x, ax);
    r.y = wd * fmaf(wd, xv.y, ay);
    *(float2*)(out + ((size_t)wid << 8) + 2 * lane) = r;
}

// ---------------------------------------------------------------------------
// Fallback path (small workspace): original init + atomic scatter.
// ---------------------------------------------------------------------------
__global__ void k_agg_init(const float* __restrict__ x0,
                           const float* __restrict__ dinv,
                           float* __restrict__ out) {
    int i = blockIdx.x * blockDim.x + threadIdx.x;   // over NROW*Fn = 10.24M
    if (i >= NROW * Fn) return;
    int r = i >> 7;
    int c = i & 127;
    float dv = dinv[r];
    out[((size_t)r << 8) + c] = dv * dv * x0[i];     // self-loop term
}

__global__ void k_scatter(const int* __restrict__ e,
                          const float* __restrict__ dinv,
                          const float* __restrict__ x0,
                          float* __restrict__ out) {
    bool i64 = edge_is_i64(e);
    long long gid = (long long)blockIdx.x * blockDim.x + threadIdx.x;
    int eid = (int)(gid >> 6);
    int lane = (int)(gid & 63);
    if (eid >= NEDGE) return;
    int b = eid / En, k = eid - b * En;
    int src = eidx(e, (long long)(b * 2) * En + k, i64);
    int dst = eidx(e, (long long)(b * 2 + 1) * En + k, i64);
    if ((unsigned)src >= Nn || (unsigned)dst >= Nn) return;
    float nrm = dinv[b * Nn + src] * dinv[b * Nn + dst];
    const float2 vf =
        *(const float2*)(x0 + ((size_t)(b * Nn + src) << 7) + 2 * lane);
    float* p = out + ((size_t)(b * Nn + dst) << 8) + 2 * lane;
    atomicAdd(p, nrm * vf.x);
    atomicAdd(p + 1, nrm * vf.y);
}

// ---------------------------------------------------------------------------
// Row-tiled fused epilogue: 32 rows/block, 256 threads.
//   rs = relu(AGG@Wc + bc) + x0 ; hs = leaky(rs@W1 + b1) ;
//   out = leaky(hs@W2 + b2)  [all f32]
// Register tiles: 4x4 (conv), 4x8 (MLPs). LDS overlay keeps 49,408 B:
//   [rs 32x129 | ag 32x129] ; hs (32x257) overlays ag (dead after stage A).
// Padding (+1 col) de-aliases the stride-128 bank pattern of A-column reads.
// ---------------------------------------------------------------------------
__global__ __launch_bounds__(256, 3) void k_fused(
        const float* __restrict__ x0,
        const float* __restrict__ Wc, const float* __restrict__ bc,
        const float* __restrict__ W1, const float* __restrict__ b1,
        const float* __restrict__ W2, const float* __restrict__ b2,
        float* out) {
    __shared__ float smem[12352];                     // 49,408 B
    float (*rs)[Fn + 1] = (float (*)[Fn + 1])smem;            // 32x129
    float (*ag)[Fn + 1] = (float (*)[Fn + 1])(smem + 4128);   // 32x129
    float (*hs)[Hn + 1] = (float (*)[Hn + 1])(smem + 4128);   // 32x257 (overlays ag)

    int row0 = blockIdx.x * TM;
    int t = threadIdx.x;
    int tx = t & 31;          // 32 column-groups
    int ty = t >> 5;          // 8 row-groups
    int ra = ty * 4;          // this thread's 4 rows

    // load AGG tile (32x128) from out's strided rows
    for (int i = t; i < TM * Fn; i += 256) {
        int r = i >> 7, c = i & 127;
        ag[r][c] = out[((size_t)(row0 + r) << 8) + c];
    }
    __syncthreads();

    // ---- stage A: rs = relu(ag@Wc + bc) + x0  (tile 32x128, 4x4/thread) ----
    {
        float acc[4][4] = {};
#pragma unroll 4
        for (int k = 0; k < Fn; ++k) {
            float a0 = ag[ra + 0][k], a1 = ag[ra + 1][k],
                  a2 = ag[ra + 2][k], a3 = ag[ra + 3][k];
            const float4 b = *(const float4*)(Wc + k * Fn + tx * 4);
            acc[0][0] = fmaf(a0, b.x, acc[0][0]); acc[0][1] = fmaf(a0, b.y, acc[0][1]);
            acc[0][2] = fmaf(a0, b.z, acc[0][2]); acc[0][3] = fmaf(a0, b.w, acc[0][3]);
            acc[1][0] = fmaf(a1, b.x, acc[1][0]); acc[1][1] = fmaf(a1, b.y, acc[1][1]);
            acc[1][2] = fmaf(a1, b.z, acc[1][2]); acc[1][3] = fmaf(a1, b.w, acc[1][3]);
            acc[2][0] = fmaf(a2, b.x, acc[2][0]); acc[2][1] = fmaf(a2, b.y, acc[2][1]);
            acc[2][2] = fmaf(a2, b.z, acc[2][2]); acc[2][3] = fmaf(a2, b.w, acc[2][3]);
            acc[3][0] = fmaf(a3, b.x, acc[3][0]); acc[3][1] = fmaf(a3, b.y, acc[3][1]);
            acc[3][2] = fmaf(a3, b.z, acc[3][2]); acc[3][3] = fmaf(a3, b.w, acc[3][3]);
        }
        const float4 bcv = *(const float4*)(bc + tx * 4);
        __syncthreads();   // order A-reads of ag vs B's hs-writes (overlay)
#pragma unroll
        for (int i = 0; i < 4; ++i) {
            const float4 xv =
                *(const float4*)(x0 + (size_t)(row0 + ra + i) * Fn + tx * 4);
            rs[ra + i][tx * 4 + 0] = fmaxf(acc[i][0] + bcv.x, 0.f) + xv.x;
            rs[ra + i][tx * 4 + 1] = fmaxf(acc[i][1] + bcv.y, 0.f) + xv.y;
            rs[ra + i][tx * 4 + 2] = fmaxf(acc[i][2] + bcv.z, 0.f) + xv.z;
            rs[ra + i][tx * 4 + 3] = fmaxf(acc[i][3] + bcv.w, 0.f) + xv.w;
        }
    }
    __syncthreads();

    // ---- stage B: hs = leaky(rs@W1 + b1)  (tile 32x256, 4x8/thread) ----
    {
        float acc[4][8] = {};
#pragma unroll 2
        for (int k = 0; k < Fn; ++k) {
            float a0 = rs[ra + 0][k], a1 = rs[ra + 1][k],
                  a2 = rs[ra + 2][k], a3 = rs[ra + 3][k];
            const float4 p0 = *(const float4*)(W1 + k * Hn + tx * 8);
            const float4 p1 = *(const float4*)(W1 + k * Hn + tx * 8 + 4);
#pragma unroll
            for (int i = 0; i < 4; ++i) {
                float a = (i == 0) ? a0 : (i == 1) ? a1 : (i == 2) ? a2 : a3;
                acc[i][0] = fmaf(a, p0.x, acc[i][0]); acc[i][1] = fmaf(a, p0.y, acc[i][1]);
                acc[i][2] = fmaf(a, p0.z, acc[i][2]); acc[i][3] = fmaf(a, p0.w, acc[i][3]);
                acc[i][4] = fmaf(a, p1.x, acc[i][4]); acc[i][5] = fmaf(a, p1.y, acc[i][5]);
                acc[i][6] = fmaf(a, p1.z, acc[i][6]); acc[i][7] = fmaf(a, p1.w, acc[i][7]);
            }
        }
        const float4 b1a = *(const float4*)(b1 + tx * 8);
        const float4 b1b = *(const float4*)(b1 + tx * 8 + 4);
        float bias[8] = {b1a.x, b1a.y, b1a.z, b1a.w, b1b.x, b1b.y, b1b.z, b1b.w};
#pragma unroll
        for (int i = 0; i < 4; ++i)
#pragma unroll
            for (int j = 0; j < 8; ++j) {
                float h = acc[i][j] + bias[j];
                hs[ra + i][tx * 8 + j] = h > 0.f ? h : 0.01f * h;
            }
    }
    __syncthreads();

    // ---- stage C: out = leaky(hs@W2 + b2)  (tile 32x256, 4x8/thread) ----
    {
        float acc[4][8] = {};
#pragma unroll 2
        for (int k = 0; k < Hn; ++k) {
            float a0 = hs[ra + 0][k], a1 = hs[ra + 1][k],
                  a2 = hs[ra + 2][k], a3 = hs[ra + 3][k];
            const float4 p0 = *(const float4*)(W2 + k * Hn + tx * 8);
            const float4 p1 = *(const float4*)(W2 + k * Hn + tx * 8 + 4);
#pragma unroll
            for (int i = 0; i < 4; ++i) {
                float a = (i == 0) ? a0 : (i == 1) ? a1 : (i == 2) ? a2 : a3;
                acc[i][0] = fmaf(a, p0.x, acc[i][0]); acc[i][1] = fmaf(a, p0.y, acc[i][1]);
                acc[i][2] = fmaf(a, p0.z, acc[i][2]); acc[i][3] = fmaf(a, p0.w, acc[i][3]);
                acc[i][4] = fmaf(a, p1.x, acc[i][4]); acc[i][5] = fmaf(a, p1.y, acc[i][5]);
                acc[i][6] = fmaf(a, p1.z, acc[i][6]); acc[i][7] = fmaf(a, p1.w, acc[i][7]);
            }
        }
        const float4 b2a = *(const float4*)(b2 + tx * 8);
        const float4 b2b = *(const float4*)(b2 + tx * 8 + 4);
        float bias[8] = {b2a.x, b2a.y, b2a.z, b2a.w, b2b.x, b2b.y, b2b.z, b2b.w};
#pragma unroll
        for (int i = 0; i < 4; ++i) {
            float o[8];
#pragma unroll
            for (int j = 0; j < 8; ++j) {
                float v = acc[i][j] + bias[j];
                o[j] = v > 0.f ? v : 0.01f * v;
            }
            float* dst = out + ((size_t)(row0 + ra + i) << 8) + tx * 8;
            *(float4*)(dst)     = make_float4(o[0], o[1], o[2], o[3]);
            *(float4*)(dst + 4) = make_float4(o[4], o[5], o[6], o[7]);
        }
    }
}

// ---------------------------------------------------------------------------
extern "C" void kernel_launch(void* const* d_in, const int* in_sizes, int n_in,
                              void* d_out, int out_size, void* d_ws, size_t ws_size,
                              hipStream_t stream) {
    const float* x0 = (const float*)d_in[0];
    const int*   ed = (const int*)d_in[1];
    const float* Wc = (const float*)d_in[2];
    const float* bc = (const float*)d_in[3];
    const float* W1 = (const float*)d_in[4];
    const float* b1 = (const float*)d_in[5];
    const float* W2 = (const float*)d_in[6];
    const float* b2 = (const float*)d_in[7];

    float* out = (float*)d_out;             // f32 output; AGG strided inside
    float* deg = (float*)d_ws;
    int*   wsi = (int*)d_ws;

    k_canary<<<1, 64, 0, stream>>>(out);
    k_deg_init<<<(NROW + 255) / 256, 256, 0, stream>>>(deg);
    k_deg_count<<<(NEDGE + 255) / 256, 256, 0, stream>>>(ed, deg);

    if (ws_size >= (size_t)WS_INTS * 4) {
        // --- CSR build + gather path (no f32 atomics) ---
        int* row_start = wsi + OFF_RS;
        int* cursor    = wsi + OFF_CUR;
        int* elist     = wsi + OFF_EL;
        int* bsum      = wsi + OFF_BS;
        int* boff      = wsi + OFF_BO;

        k_scan1<<<313, 256, 0, stream>>>(deg, row_start, bsum);
        k_scan2<<<1, 512, 0, stream>>>(bsum, boff, row_start);
        k_scan3<<<313, 256, 0, stream>>>(deg, row_start, boff, cursor);   // + dinv
        k_bin<<<(NEDGE + 255) / 256, 256, 0, stream>>>(ed, cursor, elist);
        k_gather<<<(NROW * 64 + 255) / 256, 256, 0, stream>>>(
            x0, deg, row_start, cursor, elist, out);
    } else {
        // --- fallback: original atomic scatter ---
        k_dinv<<<(NROW + 255) / 256, 256, 0, stream>>>(deg);
        k_agg_init<<<(NROW * Fn + 255) / 256, 256, 0, stream>>>(x0, deg, out);
        long long sthreads = (long long)NEDGE * 64;
        k_scatter<<<(int)((sthreads + 255) / 256), 256, 0, stream>>>(ed, deg, x0, out);
    }

    k_fused<<<NROW / TM, 256, 0, stream>>>(x0, Wc, bc, W1, b1, W2, b2, out);
}

// Round 2
// 423.290 us; speedup vs baseline: 3.8319x; 1.6675x over previous
//
#include <hip/hip_runtime.h>
#include <hip/hip_bf16.h>

// Problem constants: B=8, N=10000, E=160000, F=128, H=256
#define Bn 8
#define Nn 10000
#define En 160000
#define Fn 128
#define Hn 256
#define NROW (Bn * Nn)     // 80,000
#define NEDGE (Bn * En)    // 1,280,000
#define TM 32              // rows per block in fused epilogue

// Workspace layout (ints):
//   [0,80000)            deg (f32) -> dinv after k_scan3
//   [80000,160001)       row_start
//   [160004,240004)      cursor
//   [240004,1520004)     elist
//   [1520004,1520317)    bsum
//   [1520320,1520832)    boff
//   then 458,752 B of packed split-bf16 weights (u16), 16B-aligned.
#define OFF_RS  80000
#define OFF_CUR 160004
#define OFF_EL  240004
#define OFF_BS  1520004
#define OFF_BO  1520320
#define WS_INTS 1520832
#define WP_BYTES 458752
#define WS_MFMA_BYTES ((size_t)WS_INTS * 4 + WP_BYTES)

typedef unsigned short u16;
typedef __attribute__((ext_vector_type(8))) short s16x8;
typedef __attribute__((ext_vector_type(4))) float f32x4;

__device__ __forceinline__ u16 f2bf(float x) {           // RNE f32->bf16
    unsigned u = __float_as_uint(x);
    u += 0x7FFF + ((u >> 16) & 1);
    return (u16)(u >> 16);
}
__device__ __forceinline__ float bf2f(u16 h) {
    return __uint_as_float((unsigned)h << 16);
}

__global__ void k_canary(float* out) {
    if (threadIdx.x == 0 && blockIdx.x == 0)
        out[4] = 1000.0f;   // erased by k_gather / k_agg_init
}

// ---------------------------------------------------------------------------
// Degree: 1 (self-loop) + #incoming edges.
// ---------------------------------------------------------------------------
__global__ void k_deg_init(float* __restrict__ deg) {
    int i = blockIdx.x * blockDim.x + threadIdx.x;
    if (i < NROW) deg[i] = 1.0f;
}

__device__ __forceinline__ bool edge_is_i64(const int* e) {
    return e[1] == 0 && e[3] == 0;
}
__device__ __forceinline__ int eidx(const int* e, long long i, bool i64) {
    return i64 ? e[2 * i] : e[i];
}

__global__ void k_deg_count(const int* __restrict__ e, float* __restrict__ deg) {
    bool i64 = edge_is_i64(e);
    int i = blockIdx.x * blockDim.x + threadIdx.x;
    if (i >= NEDGE) return;
    int b = i / En, k = i - b * En;
    int dst = eidx(e, (long long)(b * 2 + 1) * En + k, i64);
    if ((unsigned)dst < Nn) atomicAdd(&deg[b * Nn + dst], 1.0f);
}

__global__ void k_dinv(float* __restrict__ deg) {   // fallback path only
    int i = blockIdx.x * blockDim.x + threadIdx.x;
    if (i < NROW) deg[i] = rsqrtf(deg[i]);
}

// ---------------------------------------------------------------------------
// Exclusive scan of in-degree over 80,000 rows, 3 kernels.
// ---------------------------------------------------------------------------
__global__ void k_scan1(const float* __restrict__ deg,
                        int* __restrict__ row_start, int* __restrict__ bsum) {
    __shared__ int s[256];
    int i = blockIdx.x * 256 + threadIdx.x;
    int v = (i < NROW) ? ((int)deg[i] - 1) : 0;
    s[threadIdx.x] = v;
    __syncthreads();
    for (int off = 1; off < 256; off <<= 1) {
        int t = (threadIdx.x >= off) ? s[threadIdx.x - off] : 0;
        __syncthreads();
        s[threadIdx.x] += t;
        __syncthreads();
    }
    if (i < NROW) row_start[i] = s[threadIdx.x] - v;
    if (threadIdx.x == 255) bsum[blockIdx.x] = s[255];
}

__global__ void k_scan2(const int* __restrict__ bsum, int* __restrict__ boff,
                        int* __restrict__ row_start) {
    __shared__ int s[512];
    int t = threadIdx.x;
    int v = (t < 313) ? bsum[t] : 0;
    s[t] = v;
    __syncthreads();
    for (int off = 1; off < 512; off <<= 1) {
        int u = (t >= off) ? s[t - off] : 0;
        __syncthreads();
        s[t] += u;
        __syncthreads();
    }
    boff[t] = s[t] - v;
    if (t == 511) row_start[NROW] = s[511];
}

__global__ void k_scan3(float* __restrict__ deg, int* __restrict__ row_start,
                        const int* __restrict__ boff, int* __restrict__ cursor) {
    int i = blockIdx.x * blockDim.x + threadIdx.x;
    if (i >= NROW) return;
    int v = row_start[i] + boff[i >> 8];
    row_start[i] = v;
    cursor[i] = v;
    deg[i] = rsqrtf(deg[i]);
}

// ---------------------------------------------------------------------------
// Counting-sort edges by destination.
// ---------------------------------------------------------------------------
__global__ void k_bin(const int* __restrict__ e, int* __restrict__ cursor,
                      int* __restrict__ elist) {
    bool i64 = edge_is_i64(e);
    int i = blockIdx.x * blockDim.x + threadIdx.x;
    if (i >= NEDGE) return;
    int b = i / En, k = i - b * En;
    int src = eidx(e, (long long)(b * 2) * En + k, i64);
    int dst = eidx(e, (long long)(b * 2 + 1) * En + k, i64);
    if ((unsigned)src >= Nn || (unsigned)dst >= Nn) return;
    int pos = atomicAdd(&cursor[b * Nn + dst], 1);
    elist[pos] = b * Nn + src;
}

// ---------------------------------------------------------------------------
// Gather aggregation: one wave per destination row, 2 cols/lane.
// ---------------------------------------------------------------------------
__global__ __launch_bounds__(256) void k_gather(
        const float* __restrict__ x0, const float* __restrict__ dinv,
        const int* __restrict__ row_start, const int* __restrict__ row_end,
        const int* __restrict__ elist, float* __restrict__ out) {
    int wid = (blockIdx.x * 256 + threadIdx.x) >> 6;
    int lane = threadIdx.x & 63;
    if (wid >= NROW) return;
    int rs = row_start[wid], re = row_end[wid];
    float ax = 0.f, ay = 0.f;
    int j = rs;
    for (; j + 4 <= re; j += 4) {
        int s0 = elist[j], s1 = elist[j + 1], s2 = elist[j + 2], s3 = elist[j + 3];
        float w0 = dinv[s0], w1 = dinv[s1], w2 = dinv[s2], w3 = dinv[s3];
        const float2 v0 = *(const float2*)(x0 + ((size_t)s0 << 7) + 2 * lane);
        const float2 v1 = *(const float2*)(x0 + ((size_t)s1 << 7) + 2 * lane);
        const float2 v2 = *(const float2*)(x0 + ((size_t)s2 << 7) + 2 * lane);
        const float2 v3 = *(const float2*)(x0 + ((size_t)s3 << 7) + 2 * lane);
        ax = fmaf(w0, v0.x, ax); ay = fmaf(w0, v0.y, ay);
        ax = fmaf(w1, v1.x, ax); ay = fmaf(w1, v1.y, ay);
        ax = fmaf(w2, v2.x, ax); ay = fmaf(w2, v2.y, ay);
        ax = fmaf(w3, v3.x, ax); ay = fmaf(w3, v3.y, ay);
    }
    for (; j < re; ++j) {
        int s = elist[j];
        float w = dinv[s];
        const float2 v = *(const float2*)(x0 + ((size_t)s << 7) + 2 * lane);
        ax = fmaf(w, v.x, ax); ay = fmaf(w, v.y, ay);
    }
    float wd = dinv[wid];
    const float2 xv = *(const float2*)(x0 + ((size_t)wid << 7) + 2 * lane);
    float2 r;
    r.x = wd * fmaf(wd, xv.x, ax);
    r.y = wd * fmaf(wd, xv.y, ay);
    *(float2*)(out + ((size_t)wid << 8) + 2 * lane) = r;
}

// ---------------------------------------------------------------------------
// Weight pre-split + pre-swizzle into MFMA B-fragment order.
// Per weight: [kt][nt][h(hi/lo)][lane 64][8 f16-slots] of bf16 (u16).
// Fragment k-map: k = kt*32 + (l>>4)*8 + j  (same map used for A-frags, so
// any consistent bijection is correct).
// Regions (u16): Wc @0 (32768), W1 @32768 (65536), W2 @98304 (131072).
// ---------------------------------------------------------------------------
__global__ void k_wpack(const float* __restrict__ Wc, const float* __restrict__ W1,
                        const float* __restrict__ W2, u16* __restrict__ wp) {
    int i = blockIdx.x * 256 + threadIdx.x;
    const float* W; u16* dst; int NT, idx;
    if (i < 16384)       { W = Wc; dst = wp;         NT = 8;  idx = i; }
    else if (i < 49152)  { W = W1; dst = wp + 32768; NT = 16; idx = i - 16384; }
    else if (i < 114688) { W = W2; dst = wp + 98304; NT = 16; idx = i - 49152; }
    else return;
    int j  = idx & 7;
    int l  = (idx >> 3) & 63;
    int nt = (idx >> 9) % NT;
    int kt = (idx >> 9) / NT;
    int k = kt * 32 + (l >> 4) * 8 + j;
    int n = nt * 16 + (l & 15);
    int N = NT * 16;
    float v = W[(size_t)k * N + n];
    u16 hi = f2bf(v);
    u16 lo = f2bf(v - bf2f(hi));
    int o = (kt * NT + nt) * 1024 + l * 8 + j;   // h=0 block
    dst[o] = hi;
    dst[o + 512] = lo;                            // h=1 block
}

// ---------------------------------------------------------------------------
// MFMA fused epilogue (split-bf16, 3 MFMAs per logical f32 product).
// 32 rows/block, 256 threads = 4 waves. Wave w handles BOTH m-tiles for a
// disjoint n-range (weights read exactly once per block).
// LDS (u16, 51,200 B): rs_hi[32][136] rs_lo | {ag_hi,ag_lo}[32][136] overlaid
// by hs_{hi,lo}[32][264]. Row pads (+8 u16) make row stride an odd # of 16B
// units -> conflict-free ds_read_b128 fragments.
// MFMA layouts (m89/m91-verified): C/D col=lane&15, row=(lane>>4)*4+reg.
// A frag: row=lane&15, k-slot=(lane>>4)*8+j (same k-map as packed B).
// ---------------------------------------------------------------------------
__global__ __launch_bounds__(256, 3) void k_fmfma(
        const float* __restrict__ x0, const u16* __restrict__ wp,
        const float* __restrict__ bc, const float* __restrict__ b1,
        const float* __restrict__ b2, float* out) {
    __shared__ __align__(16) u16 sm[25600];
    u16* rs_hi = sm;              // [32][136]
    u16* rs_lo = sm + 4352;
    u16* ag_hi = sm + 8704;       // [32][136]
    u16* ag_lo = sm + 13056;
    u16* hs_hi = sm + 8704;       // [32][264] overlays ag (dead after stage A)
    u16* hs_lo = sm + 17152;

    int row0 = blockIdx.x * TM;
    int t = threadIdx.x;
    int w = t >> 6;               // wave 0..3
    int l = t & 63;
    int lr = l & 15;              // A-frag row / C col
    int lg = l >> 4;              // k-group / C row-group

    // ---- phase 0: load AGG (32x128 f32), split into hi/lo bf16 LDS planes ----
#pragma unroll
    for (int it = 0; it < 8; ++it) {
        int i = (it * 256 + t) * 2;
        int r = i >> 7, c = i & 127;
        float2 v = *(const float2*)(out + ((size_t)(row0 + r) << 8) + c);
        u16 h0 = f2bf(v.x), h1 = f2bf(v.y);
        u16 q0 = f2bf(v.x - bf2f(h0)), q1 = f2bf(v.y - bf2f(h1));
        ((unsigned*)ag_hi)[r * 68 + (c >> 1)] = (unsigned)h0 | ((unsigned)h1 << 16);
        ((unsigned*)ag_lo)[r * 68 + (c >> 1)] = (unsigned)q0 | ((unsigned)q1 << 16);
    }
    __syncthreads();

    // ---- stage A: conv = ag@Wc (32x128); wave w: nt in {2w,2w+1}, both m ----
    {
        f32x4 acc[2][2];
#pragma unroll
        for (int mi = 0; mi < 2; ++mi)
#pragma unroll
            for (int ni = 0; ni < 2; ++ni) acc[mi][ni] = (f32x4){0.f, 0.f, 0.f, 0.f};
#pragma unroll
        for (int kt = 0; kt < 4; ++kt) {
            int ka = kt * 32 + lg * 8;
            s16x8 a0h = *(const s16x8*)(ag_hi + lr * 136 + ka);
            s16x8 a0l = *(const s16x8*)(ag_lo + lr * 136 + ka);
            s16x8 a1h = *(const s16x8*)(ag_hi + (16 + lr) * 136 + ka);
            s16x8 a1l = *(const s16x8*)(ag_lo + (16 + lr) * 136 + ka);
#pragma unroll
            for (int ni = 0; ni < 2; ++ni) {
                int nt = 2 * w + ni;
                const u16* bp = wp + (kt * 8 + nt) * 1024 + l * 8;
                s16x8 bh = *(const s16x8*)(bp);
                s16x8 bl = *(const s16x8*)(bp + 512);
                acc[0][ni] = __builtin_amdgcn_mfma_f32_16x16x32_bf16(a0h, bl, acc[0][ni], 0, 0, 0);
                acc[0][ni] = __builtin_amdgcn_mfma_f32_16x16x32_bf16(a0l, bh, acc[0][ni], 0, 0, 0);
                acc[0][ni] = __builtin_amdgcn_mfma_f32_16x16x32_bf16(a0h, bh, acc[0][ni], 0, 0, 0);
                acc[1][ni] = __builtin_amdgcn_mfma_f32_16x16x32_bf16(a1h, bl, acc[1][ni], 0, 0, 0);
                acc[1][ni] = __builtin_amdgcn_mfma_f32_16x16x32_bf16(a1l, bh, acc[1][ni], 0, 0, 0);
                acc[1][ni] = __builtin_amdgcn_mfma_f32_16x16x32_bf16(a1h, bh, acc[1][ni], 0, 0, 0);
            }
        }
        // epilogue: rs = relu(conv + bc) + x0, split to LDS
#pragma unroll
        for (int ni = 0; ni < 2; ++ni) {
            int col = (2 * w + ni) * 16 + lr;
            float bias = bc[col];
#pragma unroll
            for (int mi = 0; mi < 2; ++mi)
#pragma unroll
                for (int r = 0; r < 4; ++r) {
                    int row = mi * 16 + lg * 4 + r;
                    float v = acc[mi][ni][r] + bias;
                    v = fmaxf(v, 0.f) + x0[(size_t)(row0 + row) * Fn + col];
                    u16 h = f2bf(v);
                    rs_hi[row * 136 + col] = h;
                    rs_lo[row * 136 + col] = f2bf(v - bf2f(h));
                }
        }
    }
    __syncthreads();

    // ---- stage B: hs = leaky(rs@W1 + b1) (32x256); wave w: nt in {4w..4w+3} ----
    {
        const u16* w1p = wp + 32768;
        f32x4 acc[2][4];
#pragma unroll
        for (int mi = 0; mi < 2; ++mi)
#pragma unroll
            for (int ni = 0; ni < 4; ++ni) acc[mi][ni] = (f32x4){0.f, 0.f, 0.f, 0.f};
#pragma unroll
        for (int kt = 0; kt < 4; ++kt) {
            int ka = kt * 32 + lg * 8;
            s16x8 a0h = *(const s16x8*)(rs_hi + lr * 136 + ka);
            s16x8 a0l = *(const s16x8*)(rs_lo + lr * 136 + ka);
            s16x8 a1h = *(const s16x8*)(rs_hi + (16 + lr) * 136 + ka);
            s16x8 a1l = *(const s16x8*)(rs_lo + (16 + lr) * 136 + ka);
#pragma unroll
            for (int ni = 0; ni < 4; ++ni) {
                int nt = 4 * w + ni;
                const u16* bp = w1p + (kt * 16 + nt) * 1024 + l * 8;
                s16x8 bh = *(const s16x8*)(bp);
                s16x8 bl = *(const s16x8*)(bp + 512);
                acc[0][ni] = __builtin_amdgcn_mfma_f32_16x16x32_bf16(a0h, bl, acc[0][ni], 0, 0, 0);
                acc[0][ni] = __builtin_amdgcn_mfma_f32_16x16x32_bf16(a0l, bh, acc[0][ni], 0, 0, 0);
                acc[0][ni] = __builtin_amdgcn_mfma_f32_16x16x32_bf16(a0h, bh, acc[0][ni], 0, 0, 0);
                acc[1][ni] = __builtin_amdgcn_mfma_f32_16x16x32_bf16(a1h, bl, acc[1][ni], 0, 0, 0);
                acc[1][ni] = __builtin_amdgcn_mfma_f32_16x16x32_bf16(a1l, bh, acc[1][ni], 0, 0, 0);
                acc[1][ni] = __builtin_amdgcn_mfma_f32_16x16x32_bf16(a1h, bh, acc[1][ni], 0, 0, 0);
            }
        }
#pragma unroll
        for (int ni = 0; ni < 4; ++ni) {
            int col = (4 * w + ni) * 16 + lr;
            float bias = b1[col];
#pragma unroll
            for (int mi = 0; mi < 2; ++mi)
#pragma unroll
                for (int r = 0; r < 4; ++r) {
                    int row = mi * 16 + lg * 4 + r;
                    float v = acc[mi][ni][r] + bias;
                    v = v > 0.f ? v : 0.01f * v;
                    u16 h = f2bf(v);
                    hs_hi[row * 264 + col] = h;
                    hs_lo[row * 264 + col] = f2bf(v - bf2f(h));
                }
        }
    }
    __syncthreads();

    // ---- stage C: out = leaky(hs@W2 + b2) (32x256), K=256 ----
    {
        const u16* w2p = wp + 98304;
        f32x4 acc[2][4];
#pragma unroll
        for (int mi = 0; mi < 2; ++mi)
#pragma unroll
            for (int ni = 0; ni < 4; ++ni) acc[mi][ni] = (f32x4){0.f, 0.f, 0.f, 0.f};
#pragma unroll
        for (int kt = 0; kt < 8; ++kt) {
            int ka = kt * 32 + lg * 8;
            s16x8 a0h = *(const s16x8*)(hs_hi + lr * 264 + ka);
            s16x8 a0l = *(const s16x8*)(hs_lo + lr * 264 + ka);
            s16x8 a1h = *(const s16x8*)(hs_hi + (16 + lr) * 264 + ka);
            s16x8 a1l = *(const s16x8*)(hs_lo + (16 + lr) * 264 + ka);
#pragma unroll
            for (int ni = 0; ni < 4; ++ni) {
                int nt = 4 * w + ni;
                const u16* bp = w2p + (kt * 16 + nt) * 1024 + l * 8;
                s16x8 bh = *(const s16x8*)(bp);
                s16x8 bl = *(const s16x8*)(bp + 512);
                acc[0][ni] = __builtin_amdgcn_mfma_f32_16x16x32_bf16(a0h, bl, acc[0][ni], 0, 0, 0);
                acc[0][ni] = __builtin_amdgcn_mfma_f32_16x16x32_bf16(a0l, bh, acc[0][ni], 0, 0, 0);
                acc[0][ni] = __builtin_amdgcn_mfma_f32_16x16x32_bf16(a0h, bh, acc[0][ni], 0, 0, 0);
                acc[1][ni] = __builtin_amdgcn_mfma_f32_16x16x32_bf16(a1h, bl, acc[1][ni], 0, 0, 0);
                acc[1][ni] = __builtin_amdgcn_mfma_f32_16x16x32_bf16(a1l, bh, acc[1][ni], 0, 0, 0);
                acc[1][ni] = __builtin_amdgcn_mfma_f32_16x16x32_bf16(a1h, bh, acc[1][ni], 0, 0, 0);
            }
        }
#pragma unroll
        for (int ni = 0; ni < 4; ++ni) {
            int col = (4 * w + ni) * 16 + lr;
            float bias = b2[col];
#pragma unroll
            for (int mi = 0; mi < 2; ++mi)
#pragma unroll
                for (int r = 0; r < 4; ++r) {
                    int row = mi * 16 + lg * 4 + r;
                    float v = acc[mi][ni][r] + bias;
                    v = v > 0.f ? v : 0.01f * v;
                    out[((size_t)(row0 + row) << 8) + col] = v;
                }
        }
    }
}

// ---------------------------------------------------------------------------
// Fallback kernels (small workspace): original atomic scatter + f32 fused.
// ---------------------------------------------------------------------------
__global__ void k_agg_init(const float* __restrict__ x0,
                           const float* __restrict__ dinv,
                           float* __restrict__ out) {
    int i = blockIdx.x * blockDim.x + threadIdx.x;
    if (i >= NROW * Fn) return;
    int r = i >> 7;
    int c = i & 127;
    float dv = dinv[r];
    out[((size_t)r << 8) + c] = dv * dv * x0[i];
}

__global__ void k_scatter(const int* __restrict__ e,
                          const float* __restrict__ dinv,
                          const float* __restrict__ x0,
                          float* __restrict__ out) {
    bool i64 = edge_is_i64(e);
    long long gid = (long long)blockIdx.x * blockDim.x + threadIdx.x;
    int eid = (int)(gid >> 6);
    int lane = (int)(gid & 63);
    if (eid >= NEDGE) return;
    int b = eid / En, k = eid - b * En;
    int src = eidx(e, (long long)(b * 2) * En + k, i64);
    int dst = eidx(e, (long long)(b * 2 + 1) * En + k, i64);
    if ((unsigned)src >= Nn || (unsigned)dst >= Nn) return;
    float nrm = dinv[b * Nn + src] * dinv[b * Nn + dst];
    const float2 vf =
        *(const float2*)(x0 + ((size_t)(b * Nn + src) << 7) + 2 * lane);
    float* p = out + ((size_t)(b * Nn + dst) << 8) + 2 * lane;
    atomicAdd(p, nrm * vf.x);
    atomicAdd(p + 1, nrm * vf.y);
}

__global__ __launch_bounds__(256, 3) void k_fused(
        const float* __restrict__ x0,
        const float* __restrict__ Wc, const float* __restrict__ bc,
        const float* __restrict__ W1, const float* __restrict__ b1,
        const float* __restrict__ W2, const float* __restrict__ b2,
        float* out) {
    __shared__ float smem[12352];
    float (*rs)[Fn + 1] = (float (*)[Fn + 1])smem;
    float (*ag)[Fn + 1] = (float (*)[Fn + 1])(smem + 4128);
    float (*hs)[Hn + 1] = (float (*)[Hn + 1])(smem + 4128);

    int row0 = blockIdx.x * TM;
    int t = threadIdx.x;
    int tx = t & 31;
    int ty = t >> 5;
    int ra = ty * 4;

    for (int i = t; i < TM * Fn; i += 256) {
        int r = i >> 7, c = i & 127;
        ag[r][c] = out[((size_t)(row0 + r) << 8) + c];
    }
    __syncthreads();
    {
        float acc[4][4] = {};
#pragma unroll 4
        for (int k = 0; k < Fn; ++k) {
            float a0 = ag[ra + 0][k], a1 = ag[ra + 1][k],
                  a2 = ag[ra + 2][k], a3 = ag[ra + 3][k];
            const float4 b = *(const float4*)(Wc + k * Fn + tx * 4);
            acc[0][0] = fmaf(a0, b.x, acc[0][0]); acc[0][1] = fmaf(a0, b.y, acc[0][1]);
            acc[0][2] = fmaf(a0, b.z, acc[0][2]); acc[0][3] = fmaf(a0, b.w, acc[0][3]);
            acc[1][0] = fmaf(a1, b.x, acc[1][0]); acc[1][1] = fmaf(a1, b.y, acc[1][1]);
            acc[1][2] = fmaf(a1, b.z, acc[1][2]); acc[1][3] = fmaf(a1, b.w, acc[1][3]);
            acc[2][0] = fmaf(a2, b.x, acc[2][0]); acc[2][1] = fmaf(a2, b.y, acc[2][1]);
            acc[2][2] = fmaf(a2, b.z, acc[2][2]); acc[2][3] = fmaf(a2, b.w, acc[2][3]);
            acc[3][0] = fmaf(a3, b.x, acc[3][0]); acc[3][1] = fmaf(a3, b.y, acc[3][1]);
            acc[3][2] = fmaf(a3, b.z, acc[3][2]); acc[3][3] = fmaf(a3, b.w, acc[3][3]);
        }
        const float4 bcv = *(const float4*)(bc + tx * 4);
        __syncthreads();
#pragma unroll
        for (int i = 0; i < 4; ++i) {
            const float4 xv =
                *(const float4*)(x0 + (size_t)(row0 + ra + i) * Fn + tx * 4);
            rs[ra + i][tx * 4 + 0] = fmaxf(acc[i][0] + bcv.x, 0.f) + xv.x;
            rs[ra + i][tx * 4 + 1] = fmaxf(acc[i][1] + bcv.y, 0.f) + xv.y;
            rs[ra + i][tx * 4 + 2] = fmaxf(acc[i][2] + bcv.z, 0.f) + xv.z;
            rs[ra + i][tx * 4 + 3] = fmaxf(acc[i][3] + bcv.w, 0.f) + xv.w;
        }
    }
    __syncthreads();
    {
        float acc[4][8] = {};
#pragma unroll 2
        for (int k = 0; k < Fn; ++k) {
            float a0 = rs[ra + 0][k], a1 = rs[ra + 1][k],
                  a2 = rs[ra + 2][k], a3 = rs[ra + 3][k];
            const float4 p0 = *(const float4*)(W1 + k * Hn + tx * 8);
            const float4 p1 = *(const float4*)(W1 + k * Hn + tx * 8 + 4);
#pragma unroll
            for (int i = 0; i < 4; ++i) {
                float a = (i == 0) ? a0 : (i == 1) ? a1 : (i == 2) ? a2 : a3;
                acc[i][0] = fmaf(a, p0.x, acc[i][0]); acc[i][1] = fmaf(a, p0.y, acc[i][1]);
                acc[i][2] = fmaf(a, p0.z, acc[i][2]); acc[i][3] = fmaf(a, p0.w, acc[i][3]);
                acc[i][4] = fmaf(a, p1.x, acc[i][4]); acc[i][5] = fmaf(a, p1.y, acc[i][5]);
                acc[i][6] = fmaf(a, p1.z, acc[i][6]); acc[i][7] = fmaf(a, p1.w, acc[i][7]);
            }
        }
        const float4 b1a = *(const float4*)(b1 + tx * 8);
        const float4 b1b = *(const float4*)(b1 + tx * 8 + 4);
        float bias[8] = {b1a.x, b1a.y, b1a.z, b1a.w, b1b.x, b1b.y, b1b.z, b1b.w};
#pragma unroll
        for (int i = 0; i < 4; ++i)
#pragma unroll
            for (int j = 0; j < 8; ++j) {
                float h = acc[i][j] + bias[j];
                hs[ra + i][tx * 8 + j] = h > 0.f ? h : 0.01f * h;
            }
    }
    __syncthreads();
    {
        float acc[4][8] = {};
#pragma unroll 2
        for (int k = 0; k < Hn; ++k) {
            float a0 = hs[ra + 0][k], a1 = hs[ra + 1][k],
                  a2 = hs[ra + 2][k], a3 = hs[ra + 3][k];
            const float4 p0 = *(const float4*)(W2 + k * Hn + tx * 8);
            const float4 p1 = *(const float4*)(W2 + k * Hn + tx * 8 + 4);
#pragma unroll
            for (int i = 0; i < 4; ++i) {
                float a = (i == 0) ? a0 : (i == 1) ? a1 : (i == 2) ? a2 : a3;
                acc[i][0] = fmaf(a, p0.x, acc[i][0]); acc[i][1] = fmaf(a, p0.y, acc[i][1]);
                acc[i][2] = fmaf(a, p0.z, acc[i][2]); acc[i][3] = fmaf(a, p0.w, acc[i][3]);
                acc[i][4] = fmaf(a, p1.x, acc[i][4]); acc[i][5] = fmaf(a, p1.y, acc[i][5]);
                acc[i][6] = fmaf(a, p1.z, acc[i][6]); acc[i][7] = fmaf(a, p1.w, acc[i][7]);
            }
        }
        const float4 b2a = *(const float4*)(b2 + tx * 8);
        const float4 b2b = *(const float4*)(b2 + tx * 8 + 4);
        float bias[8] = {b2a.x, b2a.y, b2a.z, b2a.w, b2b.x, b2b.y, b2b.z, b2b.w};
#pragma unroll
        for (int i = 0; i < 4; ++i) {
            float o[8];
#pragma unroll
            for (int j = 0; j < 8; ++j) {
                float v = acc[i][j] + bias[j];
                o[j] = v > 0.f ? v : 0.01f * v;
            }
            float* dst = out + ((size_t)(row0 + ra + i) << 8) + tx * 8;
            *(float4*)(dst)     = make_float4(o[0], o[1], o[2], o[3]);
            *(float4*)(dst + 4) = make_float4(o[4], o[5], o[6], o[7]);
        }
    }
}

// ---------------------------------------------------------------------------
extern "C" void kernel_launch(void* const* d_in, const int* in_sizes, int n_in,
                              void* d_out, int out_size, void* d_ws, size_t ws_size,
                              hipStream_t stream) {
    const float* x0 = (const float*)d_in[0];
    const int*   ed = (const int*)d_in[1];
    const float* Wc = (const float*)d_in[2];
    const float* bc = (const float*)d_in[3];
    const float* W1 = (const float*)d_in[4];
    const float* b1 = (const float*)d_in[5];
    const float* W2 = (const float*)d_in[6];
    const float* b2 = (const float*)d_in[7];

    float* out = (float*)d_out;
    float* deg = (float*)d_ws;
    int*   wsi = (int*)d_ws;

    k_canary<<<1, 64, 0, stream>>>(out);
    k_deg_init<<<(NROW + 255) / 256, 256, 0, stream>>>(deg);
    k_deg_count<<<(NEDGE + 255) / 256, 256, 0, stream>>>(ed, deg);

    if (ws_size >= (size_t)WS_INTS * 4) {
        int* row_start = wsi + OFF_RS;
        int* cursor    = wsi + OFF_CUR;
        int* elist     = wsi + OFF_EL;
        int* bsum      = wsi + OFF_BS;
        int* boff      = wsi + OFF_BO;

        k_scan1<<<313, 256, 0, stream>>>(deg, row_start, bsum);
        k_scan2<<<1, 512, 0, stream>>>(bsum, boff, row_start);
        k_scan3<<<313, 256, 0, stream>>>(deg, row_start, boff, cursor);
        k_bin<<<(NEDGE + 255) / 256, 256, 0, stream>>>(ed, cursor, elist);
        k_gather<<<(NROW * 64 + 255) / 256, 256, 0, stream>>>(
            x0, deg, row_start, cursor, elist, out);

        if (ws_size >= WS_MFMA_BYTES) {
            u16* wp = (u16*)(wsi + WS_INTS);
            k_wpack<<<448, 256, 0, stream>>>(Wc, W1, W2, wp);
            k_fmfma<<<NROW / TM, 256, 0, stream>>>(x0, wp, bc, b1, b2, out);
        } else {
            k_fused<<<NROW / TM, 256, 0, stream>>>(x0, Wc, bc, W1, b1, W2, b2, out);
        }
    } else {
        k_dinv<<<(NROW + 255) / 256, 256, 0, stream>>>(deg);
        k_agg_init<<<(NROW * Fn + 255) / 256, 256, 0, stream>>>(x0, deg, out);
        long long sthreads = (long long)NEDGE * 64;
        k_scatter<<<(int)((sthreads + 255) / 256), 256, 0, stream>>>(ed, deg, x0, out);
        k_fused<<<NROW / TM, 256, 0, stream>>>(x0, Wc, bc, W1, b1, W2, b2, out);
    }
}

// Round 3
// 387.267 us; speedup vs baseline: 4.1884x; 1.0930x over previous
//
#include <hip/hip_runtime.h>
#include <hip/hip_bf16.h>
#include <hip/hip_fp16.h>

// Problem constants: B=8, N=10000, E=160000, F=128, H=256
#define Bn 8
#define Nn 10000
#define En 160000
#define Fn 128
#define Hn 256
#define NROW (Bn * Nn)     // 80,000
#define NEDGE (Bn * En)    // 1,280,000
#define TM 32              // rows per block in fused epilogue

// Workspace layout (ints):
//   [0,80000)            deg (int) -> dinv (f32) after k_scan3
//   [80000,160001)       row_start
//   [160004,240004)      cursor
//   [240004,240317)      bsum (313)
//   [240320,240832)      boff (512)
//   [240832,1520832)     elist (global src per edge, CSR order)
//   [1520832,2800832)    wlist (dinv[src] per edge)  [tier-2 only]
//   then 458,752 B packed split-bf16 weights (u16), 16B-aligned.
// out row layout (1024 B): [0,256)=AGG hi bf16, [256,512)=AGG lo bf16,
//   [512,768)=x0 row as f16 (k_xh; consumed by k_gather, overwritten by
//   k_fmfma stage C), [768,1024) free. Final k_fmfma write covers all 1024 B.
#define OFF_RS   80000
#define OFF_CUR  160004
#define OFF_BS   240004
#define OFF_BO   240320
#define OFF_EL   240832
#define OFF_WL   1520832
#define WS1_INTS 1520832
#define WS2_INTS 2800832
#define WP_BYTES 458752
#define WS1_BYTES ((size_t)WS1_INTS * 4 + WP_BYTES)   // 6,542,080 (= R2 req)
#define WS2_BYTES ((size_t)WS2_INTS * 4 + WP_BYTES)   // 11,662,080

typedef unsigned short u16;
typedef __attribute__((ext_vector_type(8))) short s16x8;
typedef __attribute__((ext_vector_type(4))) float f32x4;

__device__ __forceinline__ u16 f2bf(float x) {           // RNE f32->bf16
    unsigned u = __float_as_uint(x);
    u += 0x7FFF + ((u >> 16) & 1);
    return (u16)(u >> 16);
}
__device__ __forceinline__ float bf2f(u16 h) {
    return __uint_as_float((unsigned)h << 16);
}

// ---------------------------------------------------------------------------
// Fast-path init: int degree = 1 (self-loop) + canary poison.
// ---------------------------------------------------------------------------
__global__ void k_init(int* __restrict__ deg, float* __restrict__ out) {
    int i = blockIdx.x * blockDim.x + threadIdx.x;
    if (i < NROW) deg[i] = 1;
    if (i == 0) out[4] = 1000.0f;   // erased by k_gather's AGG write
}

// x0 -> f16, stored into out row bytes [512,768). 4 cols / thread.
__global__ void k_xh(const float* __restrict__ x0, float* __restrict__ out) {
    int i = blockIdx.x * 256 + threadIdx.x;     // < NROW*32
    if (i >= NROW * 32) return;
    int r = i >> 5, g = i & 31;
    float4 v = *(const float4*)(x0 + ((size_t)r << 7) + (g << 2));
    __half2 a = __floats2half2_rn(v.x, v.y);
    __half2 b = __floats2half2_rn(v.z, v.w);
    uint2 u;
    u.x = *(unsigned*)&a;
    u.y = *(unsigned*)&b;
    *(uint2*)((char*)out + ((size_t)r << 10) + 512 + (g << 3)) = u;
}

__device__ __forceinline__ bool edge_is_i64(const int* e) {
    return e[1] == 0 && e[3] == 0;
}
__device__ __forceinline__ int eidx(const int* e, long long i, bool i64) {
    return i64 ? e[2 * i] : e[i];
}

__global__ void k_deg_count_i(const int* __restrict__ e, int* __restrict__ deg) {
    bool i64 = edge_is_i64(e);
    int i = blockIdx.x * blockDim.x + threadIdx.x;
    if (i >= NEDGE) return;
    int b = i / En, k = i - b * En;
    int dst = eidx(e, (long long)(b * 2 + 1) * En + k, i64);
    if ((unsigned)dst < Nn) atomicAdd(&deg[b * Nn + dst], 1);
}

// ---------------------------------------------------------------------------
// Exclusive scan of in-degree over 80,000 rows, 3 kernels.
// ---------------------------------------------------------------------------
__global__ void k_scan1(const int* __restrict__ deg,
                        int* __restrict__ row_start, int* __restrict__ bsum) {
    __shared__ int s[256];
    int i = blockIdx.x * 256 + threadIdx.x;
    int v = (i < NROW) ? (deg[i] - 1) : 0;
    s[threadIdx.x] = v;
    __syncthreads();
    for (int off = 1; off < 256; off <<= 1) {
        int t = (threadIdx.x >= off) ? s[threadIdx.x - off] : 0;
        __syncthreads();
        s[threadIdx.x] += t;
        __syncthreads();
    }
    if (i < NROW) row_start[i] = s[threadIdx.x] - v;
    if (threadIdx.x == 255) bsum[blockIdx.x] = s[255];
}

__global__ void k_scan2(const int* __restrict__ bsum, int* __restrict__ boff,
                        int* __restrict__ row_start) {
    __shared__ int s[512];
    int t = threadIdx.x;
    int v = (t < 313) ? bsum[t] : 0;
    s[t] = v;
    __syncthreads();
    for (int off = 1; off < 512; off <<= 1) {
        int u = (t >= off) ? s[t - off] : 0;
        __syncthreads();
        s[t] += u;
        __syncthreads();
    }
    boff[t] = s[t] - v;
    if (t == 511) row_start[NROW] = s[511];
}

// Finalize row_start, init cursor, int degree -> f32 dinv (same buffer).
__global__ void k_scan3(int* __restrict__ degi, float* __restrict__ dinvf,
                        int* __restrict__ row_start,
                        const int* __restrict__ boff, int* __restrict__ cursor) {
    int i = blockIdx.x * blockDim.x + threadIdx.x;
    if (i >= NROW) return;
    int v = row_start[i] + boff[i >> 8];
    row_start[i] = v;
    cursor[i] = v;
    float d = (float)degi[i];
    dinvf[i] = rsqrtf(d);
}

// ---------------------------------------------------------------------------
// Counting-sort edges by destination; optionally materialize weights.
// ---------------------------------------------------------------------------
__global__ void k_bin(const int* __restrict__ e, const float* __restrict__ dinv,
                      int* __restrict__ cursor, int* __restrict__ elist,
                      float* __restrict__ wl) {
    bool i64 = edge_is_i64(e);
    int i = blockIdx.x * blockDim.x + threadIdx.x;
    if (i >= NEDGE) return;
    int b = i / En, k = i - b * En;
    int src = eidx(e, (long long)(b * 2) * En + k, i64);
    int dst = eidx(e, (long long)(b * 2 + 1) * En + k, i64);
    if ((unsigned)src >= Nn || (unsigned)dst >= Nn) return;
    int gsrc = b * Nn + src;
    int pos = atomicAdd(&cursor[b * Nn + dst], 1);
    elist[pos] = gsrc;
    if (wl) wl[pos] = dinv[gsrc];
}

// ---------------------------------------------------------------------------
// Gather aggregation: one wave per destination row, 2 cols/lane.
// Reads f16 x0 copies from out rows' bytes [512,768); writes AGG as packed
// bf16 hi plane (bytes [0,256)) + lo plane ([256,512)).
// ---------------------------------------------------------------------------
__device__ __forceinline__ void g_edge(const char* __restrict__ outc, int s,
                                       float w, int lane, float& ax, float& ay) {
    __half2 h = *(const __half2*)(outc + ((size_t)s << 10) + 512 + 4 * lane);
    float2 v = __half22float2(h);
    ax = fmaf(w, v.x, ax);
    ay = fmaf(w, v.y, ay);
}

__global__ __launch_bounds__(256) void k_gather(
        const float* __restrict__ dinv,
        const int* __restrict__ row_start, const int* __restrict__ row_end,
        const int* __restrict__ elist, const float* __restrict__ wl,
        float* __restrict__ out) {
    int wid = (blockIdx.x * 256 + threadIdx.x) >> 6;
    int lane = threadIdx.x & 63;
    if (wid >= NROW) return;
    const char* outc = (const char*)out;
    int rs = row_start[wid], re = row_end[wid];
    float ax = 0.f, ay = 0.f;
    int j = rs;
    if (wl) {
        // peel to 16B alignment of elist/wlist
        while (j < re && (j & 3)) { g_edge(outc, elist[j], wl[j], lane, ax, ay); ++j; }
        for (; j + 8 <= re; j += 8) {
            int4   ea = *(const int4*)(elist + j);
            int4   eb = *(const int4*)(elist + j + 4);
            float4 wa = *(const float4*)(wl + j);
            float4 wb = *(const float4*)(wl + j + 4);
            g_edge(outc, ea.x, wa.x, lane, ax, ay);
            g_edge(outc, ea.y, wa.y, lane, ax, ay);
            g_edge(outc, ea.z, wa.z, lane, ax, ay);
            g_edge(outc, ea.w, wa.w, lane, ax, ay);
            g_edge(outc, eb.x, wb.x, lane, ax, ay);
            g_edge(outc, eb.y, wb.y, lane, ax, ay);
            g_edge(outc, eb.z, wb.z, lane, ax, ay);
            g_edge(outc, eb.w, wb.w, lane, ax, ay);
        }
        if (j + 4 <= re) {
            int4   ea = *(const int4*)(elist + j);
            float4 wa = *(const float4*)(wl + j);
            g_edge(outc, ea.x, wa.x, lane, ax, ay);
            g_edge(outc, ea.y, wa.y, lane, ax, ay);
            g_edge(outc, ea.z, wa.z, lane, ax, ay);
            g_edge(outc, ea.w, wa.w, lane, ax, ay);
            j += 4;
        }
        for (; j < re; ++j) g_edge(outc, elist[j], wl[j], lane, ax, ay);
    } else {
        for (; j + 4 <= re; j += 4) {
            int s0 = elist[j], s1 = elist[j + 1], s2 = elist[j + 2], s3 = elist[j + 3];
            float w0 = dinv[s0], w1 = dinv[s1], w2 = dinv[s2], w3 = dinv[s3];
            g_edge(outc, s0, w0, lane, ax, ay);
            g_edge(outc, s1, w1, lane, ax, ay);
            g_edge(outc, s2, w2, lane, ax, ay);
            g_edge(outc, s3, w3, lane, ax, ay);
        }
        for (; j < re; ++j) {
            int s = elist[j];
            g_edge(outc, s, dinv[s], lane, ax, ay);
        }
    }
    // self-loop term + final dinv scale, split to bf16 hi/lo planes
    float wd = dinv[wid];
    g_edge(outc, wid, wd, lane, ax, ay);
    float sx = wd * ax, sy = wd * ay;
    u16 h0 = f2bf(sx), h1 = f2bf(sy);
    u16 l0 = f2bf(sx - bf2f(h0)), l1 = f2bf(sy - bf2f(h1));
    unsigned* orow = (unsigned*)(out + ((size_t)wid << 8));
    orow[lane]      = (unsigned)h0 | ((unsigned)h1 << 16);
    orow[64 + lane] = (unsigned)l0 | ((unsigned)l1 << 16);
}

// ---------------------------------------------------------------------------
// Weight pre-split + pre-swizzle into MFMA B-fragment order.
// Per weight: [kt][nt][h(hi/lo)][lane 64][8 slots] of bf16 (u16).
// k-map: k = kt*32 + (l>>4)*8 + j (same map as A-frags).
// Regions (u16): Wc @0 (32768), W1 @32768 (65536), W2 @98304 (131072).
// ---------------------------------------------------------------------------
__global__ void k_wpack(const float* __restrict__ Wc, const float* __restrict__ W1,
                        const float* __restrict__ W2, u16* __restrict__ wp) {
    int i = blockIdx.x * 256 + threadIdx.x;
    const float* W; u16* dst; int NT, idx;
    if (i < 16384)       { W = Wc; dst = wp;         NT = 8;  idx = i; }
    else if (i < 49152)  { W = W1; dst = wp + 32768; NT = 16; idx = i - 16384; }
    else if (i < 114688) { W = W2; dst = wp + 98304; NT = 16; idx = i - 49152; }
    else return;
    int j  = idx & 7;
    int l  = (idx >> 3) & 63;
    int nt = (idx >> 9) % NT;
    int kt = (idx >> 9) / NT;
    int k = kt * 32 + (l >> 4) * 8 + j;
    int n = nt * 16 + (l & 15);
    int N = NT * 16;
    float v = W[(size_t)k * N + n];
    u16 hi = f2bf(v);
    u16 lo = f2bf(v - bf2f(hi));
    int o = (kt * NT + nt) * 1024 + l * 8 + j;
    dst[o] = hi;
    dst[o + 512] = lo;
}

// ---------------------------------------------------------------------------
// MFMA fused epilogue (split-bf16, 3 MFMAs per logical f32 product).
// 32 rows/block, 256 threads = 4 waves; wave w owns a disjoint n-range for
// both m-tiles. Phase 0 is now a pure 16B copy (AGG arrives pre-split).
// LDS (u16, 51,200 B): rs_hi/lo [32][136]; {ag_hi,ag_lo}[32][136] overlaid
// by hs_{hi,lo}[32][264]. Row pads keep fragment ds_read_b128 conflict-free.
// ---------------------------------------------------------------------------
__global__ __launch_bounds__(256, 3) void k_fmfma(
        const float* __restrict__ x0, const u16* __restrict__ wp,
        const float* __restrict__ bc, const float* __restrict__ b1,
        const float* __restrict__ b2, float* out) {
    __shared__ __align__(16) u16 sm[25600];
    u16* rs_hi = sm;              // [32][136]
    u16* rs_lo = sm + 4352;
    u16* ag_hi = sm + 8704;       // [32][136]
    u16* ag_lo = sm + 13056;
    u16* hs_hi = sm + 8704;       // [32][264] overlays ag (dead after stage A)
    u16* hs_lo = sm + 17152;

    int row0 = blockIdx.x * TM;
    int t = threadIdx.x;
    int w = t >> 6;               // wave 0..3
    int l = t & 63;
    int lr = l & 15;              // A-frag row / C col
    int lg = l >> 4;              // k-group / C row-group

    // ---- phase 0: copy packed AGG planes (32 rows x 512 B) into LDS ----
#pragma unroll
    for (int it = 0; it < 4; ++it) {
        int idx = it * 256 + t;           // 0..1023
        int r = idx >> 5, q = idx & 31;   // 32 x 16B chunks per row
        uint4 v = *(const uint4*)((const char*)out +
                                  ((size_t)(row0 + r) << 10) + (q << 4));
        u16* dst = (q < 16) ? (ag_hi + r * 136 + (q << 3))
                            : (ag_lo + r * 136 + ((q - 16) << 3));
        *(uint4*)dst = v;
    }
    __syncthreads();

    // ---- stage A: conv = ag@Wc (32x128); wave w: nt in {2w,2w+1}, both m ----
    {
        f32x4 acc[2][2];
#pragma unroll
        for (int mi = 0; mi < 2; ++mi)
#pragma unroll
            for (int ni = 0; ni < 2; ++ni) acc[mi][ni] = (f32x4){0.f, 0.f, 0.f, 0.f};
#pragma unroll
        for (int kt = 0; kt < 4; ++kt) {
            int ka = kt * 32 + lg * 8;
            s16x8 a0h = *(const s16x8*)(ag_hi + lr * 136 + ka);
            s16x8 a0l = *(const s16x8*)(ag_lo + lr * 136 + ka);
            s16x8 a1h = *(const s16x8*)(ag_hi + (16 + lr) * 136 + ka);
            s16x8 a1l = *(const s16x8*)(ag_lo + (16 + lr) * 136 + ka);
#pragma unroll
            for (int ni = 0; ni < 2; ++ni) {
                int nt = 2 * w + ni;
                const u16* bp = wp + (kt * 8 + nt) * 1024 + l * 8;
                s16x8 bh = *(const s16x8*)(bp);
                s16x8 bl = *(const s16x8*)(bp + 512);
                acc[0][ni] = __builtin_amdgcn_mfma_f32_16x16x32_bf16(a0h, bl, acc[0][ni], 0, 0, 0);
                acc[0][ni] = __builtin_amdgcn_mfma_f32_16x16x32_bf16(a0l, bh, acc[0][ni], 0, 0, 0);
                acc[0][ni] = __builtin_amdgcn_mfma_f32_16x16x32_bf16(a0h, bh, acc[0][ni], 0, 0, 0);
                acc[1][ni] = __builtin_amdgcn_mfma_f32_16x16x32_bf16(a1h, bl, acc[1][ni], 0, 0, 0);
                acc[1][ni] = __builtin_amdgcn_mfma_f32_16x16x32_bf16(a1l, bh, acc[1][ni], 0, 0, 0);
                acc[1][ni] = __builtin_amdgcn_mfma_f32_16x16x32_bf16(a1h, bh, acc[1][ni], 0, 0, 0);
            }
        }
        // epilogue: rs = relu(conv + bc) + x0, split to LDS
#pragma unroll
        for (int ni = 0; ni < 2; ++ni) {
            int col = (2 * w + ni) * 16 + lr;
            float bias = bc[col];
#pragma unroll
            for (int mi = 0; mi < 2; ++mi)
#pragma unroll
                for (int r = 0; r < 4; ++r) {
                    int row = mi * 16 + lg * 4 + r;
                    float v = acc[mi][ni][r] + bias;
                    v = fmaxf(v, 0.f) + x0[(size_t)(row0 + row) * Fn + col];
                    u16 h = f2bf(v);
                    rs_hi[row * 136 + col] = h;
                    rs_lo[row * 136 + col] = f2bf(v - bf2f(h));
                }
        }
    }
    __syncthreads();

    // ---- stage B: hs = leaky(rs@W1 + b1) (32x256); wave w: nt in {4w..4w+3} ----
    {
        const u16* w1p = wp + 32768;
        f32x4 acc[2][4];
#pragma unroll
        for (int mi = 0; mi < 2; ++mi)
#pragma unroll
            for (int ni = 0; ni < 4; ++ni) acc[mi][ni] = (f32x4){0.f, 0.f, 0.f, 0.f};
#pragma unroll
        for (int kt = 0; kt < 4; ++kt) {
            int ka = kt * 32 + lg * 8;
            s16x8 a0h = *(const s16x8*)(rs_hi + lr * 136 + ka);
            s16x8 a0l = *(const s16x8*)(rs_lo + lr * 136 + ka);
            s16x8 a1h = *(const s16x8*)(rs_hi + (16 + lr) * 136 + ka);
            s16x8 a1l = *(const s16x8*)(rs_lo + (16 + lr) * 136 + ka);
#pragma unroll
            for (int ni = 0; ni < 4; ++ni) {
                int nt = 4 * w + ni;
                const u16* bp = w1p + (kt * 16 + nt) * 1024 + l * 8;
                s16x8 bh = *(const s16x8*)(bp);
                s16x8 bl = *(const s16x8*)(bp + 512);
                acc[0][ni] = __builtin_amdgcn_mfma_f32_16x16x32_bf16(a0h, bl, acc[0][ni], 0, 0, 0);
                acc[0][ni] = __builtin_amdgcn_mfma_f32_16x16x32_bf16(a0l, bh, acc[0][ni], 0, 0, 0);
                acc[0][ni] = __builtin_amdgcn_mfma_f32_16x16x32_bf16(a0h, bh, acc[0][ni], 0, 0, 0);
                acc[1][ni] = __builtin_amdgcn_mfma_f32_16x16x32_bf16(a1h, bl, acc[1][ni], 0, 0, 0);
                acc[1][ni] = __builtin_amdgcn_mfma_f32_16x16x32_bf16(a1l, bh, acc[1][ni], 0, 0, 0);
                acc[1][ni] = __builtin_amdgcn_mfma_f32_16x16x32_bf16(a1h, bh, acc[1][ni], 0, 0, 0);
            }
        }
#pragma unroll
        for (int ni = 0; ni < 4; ++ni) {
            int col = (4 * w + ni) * 16 + lr;
            float bias = b1[col];
#pragma unroll
            for (int mi = 0; mi < 2; ++mi)
#pragma unroll
                for (int r = 0; r < 4; ++r) {
                    int row = mi * 16 + lg * 4 + r;
                    float v = acc[mi][ni][r] + bias;
                    v = v > 0.f ? v : 0.01f * v;
                    u16 h = f2bf(v);
                    hs_hi[row * 264 + col] = h;
                    hs_lo[row * 264 + col] = f2bf(v - bf2f(h));
                }
        }
    }
    __syncthreads();

    // ---- stage C: out = leaky(hs@W2 + b2) (32x256), K=256 ----
    {
        const u16* w2p = wp + 98304;
        f32x4 acc[2][4];
#pragma unroll
        for (int mi = 0; mi < 2; ++mi)
#pragma unroll
            for (int ni = 0; ni < 4; ++ni) acc[mi][ni] = (f32x4){0.f, 0.f, 0.f, 0.f};
#pragma unroll
        for (int kt = 0; kt < 8; ++kt) {
            int ka = kt * 32 + lg * 8;
            s16x8 a0h = *(const s16x8*)(hs_hi + lr * 264 + ka);
            s16x8 a0l = *(const s16x8*)(hs_lo + lr * 264 + ka);
            s16x8 a1h = *(const s16x8*)(hs_hi + (16 + lr) * 264 + ka);
            s16x8 a1l = *(const s16x8*)(hs_lo + (16 + lr) * 264 + ka);
#pragma unroll
            for (int ni = 0; ni < 4; ++ni) {
                int nt = 4 * w + ni;
                const u16* bp = w2p + (kt * 16 + nt) * 1024 + l * 8;
                s16x8 bh = *(const s16x8*)(bp);
                s16x8 bl = *(const s16x8*)(bp + 512);
                acc[0][ni] = __builtin_amdgcn_mfma_f32_16x16x32_bf16(a0h, bl, acc[0][ni], 0, 0, 0);
                acc[0][ni] = __builtin_amdgcn_mfma_f32_16x16x32_bf16(a0l, bh, acc[0][ni], 0, 0, 0);
                acc[0][ni] = __builtin_amdgcn_mfma_f32_16x16x32_bf16(a0h, bh, acc[0][ni], 0, 0, 0);
                acc[1][ni] = __builtin_amdgcn_mfma_f32_16x16x32_bf16(a1h, bl, acc[1][ni], 0, 0, 0);
                acc[1][ni] = __builtin_amdgcn_mfma_f32_16x16x32_bf16(a1l, bh, acc[1][ni], 0, 0, 0);
                acc[1][ni] = __builtin_amdgcn_mfma_f32_16x16x32_bf16(a1h, bh, acc[1][ni], 0, 0, 0);
            }
        }
#pragma unroll
        for (int ni = 0; ni < 4; ++ni) {
            int col = (4 * w + ni) * 16 + lr;
            float bias = b2[col];
#pragma unroll
            for (int mi = 0; mi < 2; ++mi)
#pragma unroll
                for (int r = 0; r < 4; ++r) {
                    int row = mi * 16 + lg * 4 + r;
                    float v = acc[mi][ni][r] + bias;
                    v = v > 0.f ? v : 0.01f * v;
                    out[((size_t)(row0 + row) << 8) + col] = v;
                }
        }
    }
}

// ---------------------------------------------------------------------------
// Full fallback (tiny workspace): float degree + atomic scatter + f32 fused.
// ---------------------------------------------------------------------------
__global__ void k_canary(float* out) {
    if (threadIdx.x == 0 && blockIdx.x == 0) out[4] = 1000.0f;
}
__global__ void k_deg_init(float* __restrict__ deg) {
    int i = blockIdx.x * blockDim.x + threadIdx.x;
    if (i < NROW) deg[i] = 1.0f;
}
__global__ void k_deg_count(const int* __restrict__ e, float* __restrict__ deg) {
    bool i64 = edge_is_i64(e);
    int i = blockIdx.x * blockDim.x + threadIdx.x;
    if (i >= NEDGE) return;
    int b = i / En, k = i - b * En;
    int dst = eidx(e, (long long)(b * 2 + 1) * En + k, i64);
    if ((unsigned)dst < Nn) atomicAdd(&deg[b * Nn + dst], 1.0f);
}
__global__ void k_dinv(float* __restrict__ deg) {
    int i = blockIdx.x * blockDim.x + threadIdx.x;
    if (i < NROW) deg[i] = rsqrtf(deg[i]);
}
__global__ void k_agg_init(const float* __restrict__ x0,
                           const float* __restrict__ dinv,
                           float* __restrict__ out) {
    int i = blockIdx.x * blockDim.x + threadIdx.x;
    if (i >= NROW * Fn) return;
    int r = i >> 7;
    int c = i & 127;
    float dv = dinv[r];
    out[((size_t)r << 8) + c] = dv * dv * x0[i];
}
__global__ void k_scatter(const int* __restrict__ e,
                          const float* __restrict__ dinv,
                          const float* __restrict__ x0,
                          float* __restrict__ out) {
    bool i64 = edge_is_i64(e);
    long long gid = (long long)blockIdx.x * blockDim.x + threadIdx.x;
    int eid = (int)(gid >> 6);
    int lane = (int)(gid & 63);
    if (eid >= NEDGE) return;
    int b = eid / En, k = eid - b * En;
    int src = eidx(e, (long long)(b * 2) * En + k, i64);
    int dst = eidx(e, (long long)(b * 2 + 1) * En + k, i64);
    if ((unsigned)src >= Nn || (unsigned)dst >= Nn) return;
    float nrm = dinv[b * Nn + src] * dinv[b * Nn + dst];
    const float2 vf =
        *(const float2*)(x0 + ((size_t)(b * Nn + src) << 7) + 2 * lane);
    float* p = out + ((size_t)(b * Nn + dst) << 8) + 2 * lane;
    atomicAdd(p, nrm * vf.x);
    atomicAdd(p + 1, nrm * vf.y);
}

__global__ __launch_bounds__(256, 3) void k_fused(
        const float* __restrict__ x0,
        const float* __restrict__ Wc, const float* __restrict__ bc,
        const float* __restrict__ W1, const float* __restrict__ b1,
        const float* __restrict__ W2, const float* __restrict__ b2,
        float* out) {
    __shared__ float smem[12352];
    float (*rs)[Fn + 1] = (float (*)[Fn + 1])smem;
    float (*ag)[Fn + 1] = (float (*)[Fn + 1])(smem + 4128);
    float (*hs)[Hn + 1] = (float (*)[Hn + 1])(smem + 4128);

    int row0 = blockIdx.x * TM;
    int t = threadIdx.x;
    int tx = t & 31;
    int ty = t >> 5;
    int ra = ty * 4;

    for (int i = t; i < TM * Fn; i += 256) {
        int r = i >> 7, c = i & 127;
        ag[r][c] = out[((size_t)(row0 + r) << 8) + c];
    }
    __syncthreads();
    {
        float acc[4][4] = {};
#pragma unroll 4
        for (int k = 0; k < Fn; ++k) {
            float a0 = ag[ra + 0][k], a1 = ag[ra + 1][k],
                  a2 = ag[ra + 2][k], a3 = ag[ra + 3][k];
            const float4 b = *(const float4*)(Wc + k * Fn + tx * 4);
            acc[0][0] = fmaf(a0, b.x, acc[0][0]); acc[0][1] = fmaf(a0, b.y, acc[0][1]);
            acc[0][2] = fmaf(a0, b.z, acc[0][2]); acc[0][3] = fmaf(a0, b.w, acc[0][3]);
            acc[1][0] = fmaf(a1, b.x, acc[1][0]); acc[1][1] = fmaf(a1, b.y, acc[1][1]);
            acc[1][2] = fmaf(a1, b.z, acc[1][2]); acc[1][3] = fmaf(a1, b.w, acc[1][3]);
            acc[2][0] = fmaf(a2, b.x, acc[2][0]); acc[2][1] = fmaf(a2, b.y, acc[2][1]);
            acc[2][2] = fmaf(a2, b.z, acc[2][2]); acc[2][3] = fmaf(a2, b.w, acc[2][3]);
            acc[3][0] = fmaf(a3, b.x, acc[3][0]); acc[3][1] = fmaf(a3, b.y, acc[3][1]);
            acc[3][2] = fmaf(a3, b.z, acc[3][2]); acc[3][3] = fmaf(a3, b.w, acc[3][3]);
        }
        const float4 bcv = *(const float4*)(bc + tx * 4);
        __syncthreads();
#pragma unroll
        for (int i = 0; i < 4; ++i) {
            const float4 xv =
                *(const float4*)(x0 + (size_t)(row0 + ra + i) * Fn + tx * 4);
            rs[ra + i][tx * 4 + 0] = fmaxf(acc[i][0] + bcv.x, 0.f) + xv.x;
            rs[ra + i][tx * 4 + 1] = fmaxf(acc[i][1] + bcv.y, 0.f) + xv.y;
            rs[ra + i][tx * 4 + 2] = fmaxf(acc[i][2] + bcv.z, 0.f) + xv.z;
            rs[ra + i][tx * 4 + 3] = fmaxf(acc[i][3] + bcv.w, 0.f) + xv.w;
        }
    }
    __syncthreads();
    {
        float acc[4][8] = {};
#pragma unroll 2
        for (int k = 0; k < Fn; ++k) {
            float a0 = rs[ra + 0][k], a1 = rs[ra + 1][k],
                  a2 = rs[ra + 2][k], a3 = rs[ra + 3][k];
            const float4 p0 = *(const float4*)(W1 + k * Hn + tx * 8);
            const float4 p1 = *(const float4*)(W1 + k * Hn + tx * 8 + 4);
#pragma unroll
            for (int i = 0; i < 4; ++i) {
                float a = (i == 0) ? a0 : (i == 1) ? a1 : (i == 2) ? a2 : a3;
                acc[i][0] = fmaf(a, p0.x, acc[i][0]); acc[i][1] = fmaf(a, p0.y, acc[i][1]);
                acc[i][2] = fmaf(a, p0.z, acc[i][2]); acc[i][3] = fmaf(a, p0.w, acc[i][3]);
                acc[i][4] = fmaf(a, p1.x, acc[i][4]); acc[i][5] = fmaf(a, p1.y, acc[i][5]);
                acc[i][6] = fmaf(a, p1.z, acc[i][6]); acc[i][7] = fmaf(a, p1.w, acc[i][7]);
            }
        }
        const float4 b1a = *(const float4*)(b1 + tx * 8);
        const float4 b1b = *(const float4*)(b1 + tx * 8 + 4);
        float bias[8] = {b1a.x, b1a.y, b1a.z, b1a.w, b1b.x, b1b.y, b1b.z, b1b.w};
#pragma unroll
        for (int i = 0; i < 4; ++i)
#pragma unroll
            for (int j = 0; j < 8; ++j) {
                float h = acc[i][j] + bias[j];
                hs[ra + i][tx * 8 + j] = h > 0.f ? h : 0.01f * h;
            }
    }
    __syncthreads();
    {
        float acc[4][8] = {};
#pragma unroll 2
        for (int k = 0; k < Hn; ++k) {
            float a0 = hs[ra + 0][k], a1 = hs[ra + 1][k],
                  a2 = hs[ra + 2][k], a3 = hs[ra + 3][k];
            const float4 p0 = *(const float4*)(W2 + k * Hn + tx * 8);
            const float4 p1 = *(const float4*)(W2 + k * Hn + tx * 8 + 4);
#pragma unroll
            for (int i = 0; i < 4; ++i) {
                float a = (i == 0) ? a0 : (i == 1) ? a1 : (i == 2) ? a2 : a3;
                acc[i][0] = fmaf(a, p0.x, acc[i][0]); acc[i][1] = fmaf(a, p0.y, acc[i][1]);
                acc[i][2] = fmaf(a, p0.z, acc[i][2]); acc[i][3] = fmaf(a, p0.w, acc[i][3]);
                acc[i][4] = fmaf(a, p1.x, acc[i][4]); acc[i][5] = fmaf(a, p1.y, acc[i][5]);
                acc[i][6] = fmaf(a, p1.z, acc[i][6]); acc[i][7] = fmaf(a, p1.w, acc[i][7]);
            }
        }
        const float4 b2a = *(const float4*)(b2 + tx * 8);
        const float4 b2b = *(const float4*)(b2 + tx * 8 + 4);
        float bias[8] = {b2a.x, b2a.y, b2a.z, b2a.w, b2b.x, b2b.y, b2b.z, b2b.w};
#pragma unroll
        for (int i = 0; i < 4; ++i) {
            float o[8];
#pragma unroll
            for (int j = 0; j < 8; ++j) {
                float v = acc[i][j] + bias[j];
                o[j] = v > 0.f ? v : 0.01f * v;
            }
            float* dst = out + ((size_t)(row0 + ra + i) << 8) + tx * 8;
            *(float4*)(dst)     = make_float4(o[0], o[1], o[2], o[3]);
            *(float4*)(dst + 4) = make_float4(o[4], o[5], o[6], o[7]);
        }
    }
}

// ---------------------------------------------------------------------------
extern "C" void kernel_launch(void* const* d_in, const int* in_sizes, int n_in,
                              void* d_out, int out_size, void* d_ws, size_t ws_size,
                              hipStream_t stream) {
    const float* x0 = (const float*)d_in[0];
    const int*   ed = (const int*)d_in[1];
    const float* Wc = (const float*)d_in[2];
    const float* bc = (const float*)d_in[3];
    const float* W1 = (const float*)d_in[4];
    const float* b1 = (const float*)d_in[5];
    const float* W2 = (const float*)d_in[6];
    const float* b2 = (const float*)d_in[7];

    float* out = (float*)d_out;
    int*   wsi = (int*)d_ws;
    float* wsf = (float*)d_ws;

    bool t2 = ws_size >= WS2_BYTES;
    bool t1 = ws_size >= WS1_BYTES;

    if (t1 || t2) {
        int*   degi      = wsi;                 // -> dinv (f32) after scan3
        float* dinv      = wsf;
        int*   row_start = wsi + OFF_RS;
        int*   cursor    = wsi + OFF_CUR;
        int*   bsum      = wsi + OFF_BS;
        int*   boff      = wsi + OFF_BO;
        int*   elist     = wsi + OFF_EL;
        float* wl        = t2 ? (wsf + OFF_WL) : nullptr;
        u16*   wp        = (u16*)(wsi + (t2 ? WS2_INTS : WS1_INTS));

        k_init<<<313, 256, 0, stream>>>(degi, out);
        k_xh<<<10000, 256, 0, stream>>>(x0, out);
        k_deg_count_i<<<(NEDGE + 255) / 256, 256, 0, stream>>>(ed, degi);
        k_scan1<<<313, 256, 0, stream>>>(degi, row_start, bsum);
        k_scan2<<<1, 512, 0, stream>>>(bsum, boff, row_start);
        k_scan3<<<313, 256, 0, stream>>>(degi, dinv, row_start, boff, cursor);
        k_bin<<<(NEDGE + 255) / 256, 256, 0, stream>>>(ed, dinv, cursor, elist, wl);
        k_gather<<<(NROW * 64 + 255) / 256, 256, 0, stream>>>(
            dinv, row_start, cursor, elist, wl, out);
        k_wpack<<<448, 256, 0, stream>>>(Wc, W1, W2, wp);
        k_fmfma<<<NROW / TM, 256, 0, stream>>>(x0, wp, bc, b1, b2, out);
    } else {
        float* deg = wsf;
        k_canary<<<1, 64, 0, stream>>>(out);
        k_deg_init<<<(NROW + 255) / 256, 256, 0, stream>>>(deg);
        k_deg_count<<<(NEDGE + 255) / 256, 256, 0, stream>>>(ed, deg);
        k_dinv<<<(NROW + 255) / 256, 256, 0, stream>>>(deg);
        k_agg_init<<<(NROW * Fn + 255) / 256, 256, 0, stream>>>(x0, deg, out);
        long long sthreads = (long long)NEDGE * 64;
        k_scatter<<<(int)((sthreads + 255) / 256), 256, 0, stream>>>(ed, deg, x0, out);
        k_fused<<<NROW / TM, 256, 0, stream>>>(x0, Wc, bc, W1, b1, W2, b2, out);
    }
}